// Round 4
// baseline (2996.212 us; speedup 1.0000x reference)
//
#include <hip/hip_runtime.h>
#include <hip/hip_fp16.h>

typedef unsigned int uint32;
typedef unsigned long long uint64;
typedef __attribute__((ext_vector_type(8))) _Float16 half8;
typedef __attribute__((ext_vector_type(4))) float f32x4;

#define T_STEPS 512
#define BSZ 128
#define ISZ 256
#define HSZ 512
#define K1  768            // H + I, concat order (h, x)
#define NG  8              // batch groups
#define BG  16             // batch rows per group
#define GC  32             // workgroups per group (column partition)
#define NC  16             // H-columns per workgroup
#define LDK 776            // padded K stride for weights (fp16 elems)
#define LDA 264            // padded x-tile stride (fp16 elems)

// flags: per (group, rank) one 64B line; 4 u32 words = per-wave flags (rows 4w..4w+4)
#define FLAG_U32_PER_RANK 16

// LDS layout (bytes)
#define LDS_X   0                  // x tile [16][LDA] fp16
#define LDS_WZ  8448
#define LDS_WR  33280
#define LDS_WH  58112
#define LDS_SC  82944              // 3 scratch bufs [4][16][18] fp32 each (A=r, B=z, C=cand)
#define SMEM_BYTES 96768

// relaxed agent-scope atomics (bypass L1, L2-coherent)
#define AST(p, v) __hip_atomic_store((p), (v), __ATOMIC_RELAXED, __HIP_MEMORY_SCOPE_AGENT)
#define ALD(p)    __hip_atomic_load((p), __ATOMIC_RELAXED, __HIP_MEMORY_SCOPE_AGENT)

__device__ __forceinline__ float sigm(float x) {
  float e = __expf(-fabsf(x));
  float s = 1.f / (1.f + e);
  return x >= 0.f ? s : 1.f - s;
}
__device__ __forceinline__ float tanhx(float x) {
  float e = __expf(-2.f * fabsf(x));
  float t = (1.f - e) / (1.f + e);
  return x >= 0.f ? t : -t;
}
__device__ __forceinline__ uint32 f2x(float a, float b) {
  __half2 t = __floats2half2_rn(a, b);
  return *reinterpret_cast<uint32*>(&t);
}
__device__ __forceinline__ uint32 umin2(uint32 a, uint32 b) { return a < b ? a : b; }
#define MFMA(a, b, c) __builtin_amdgcn_mfma_f32_16x16x32_f16((a), (b), (c), 0, 0, 0)

union HF { uint64 u[2]; half8 h8; };

__global__ __launch_bounds__(256, 1)
void gru_persist(const float* __restrict__ x,
                 const float* __restrict__ Wz, const float* __restrict__ bz,
                 const float* __restrict__ Wr, const float* __restrict__ br,
                 const float* __restrict__ Wh, const float* __restrict__ bh,
                 float* __restrict__ out,
                 unsigned short* h_buf, unsigned short* rh_buf, uint32* flags)
{
  extern __shared__ char smem[];
  _Float16* X_l  = (_Float16*)(smem + LDS_X);
  _Float16* Wz_l = (_Float16*)(smem + LDS_WZ);
  _Float16* Wr_l = (_Float16*)(smem + LDS_WR);
  _Float16* Wh_l = (_Float16*)(smem + LDS_WH);
  float*    scA  = (float*)(smem + LDS_SC);            // r partials
  float*    scB  = scA + 1152;                          // z partials
  float*    scC  = scA + 2304;                          // cand partials

  const int tid  = threadIdx.x;
  const int g    = blockIdx.x & 7;                // group -> same XCD (round-robin dispatch)
  const int rank = blockIdx.x >> 3;
  uint32* gf = flags + (size_t)g * GC * FLAG_U32_PER_RANK;   // per-rank 64B lines
  unsigned short* hbG  = h_buf  + (size_t)g * BG * HSZ;
  unsigned short* rhbG = rh_buf + (size_t)g * BG * HSZ;

  // ---- one-time: weight slices -> LDS fp16 ----
  {
    const int r  = tid & 15;
    const int ch = tid >> 4;
    for (int mi = 0; mi < 3; ++mi) {
      const float* Ws = (mi == 0) ? Wz : (mi == 1 ? Wr : Wh);
      _Float16*    Ld = (mi == 0) ? Wz_l : (mi == 1 ? Wr_l : Wh_l);
      const float4* s = (const float4*)(Ws + (size_t)(rank * NC + r) * K1 + ch * 48);
      uint4* d = (uint4*)(Ld + r * LDK + ch * 48);
      #pragma unroll
      for (int j = 0; j < 6; ++j) {
        float4 v0 = s[2 * j], v1 = s[2 * j + 1];
        d[j] = make_uint4(f2x(v0.x, v0.y), f2x(v0.z, v0.w),
                          f2x(v1.x, v1.y), f2x(v1.z, v1.w));
      }
    }
  }

  // elementwise map: (batch bl, col cl); wave w owns rows 4w..4w+4
  const int cl = tid & 15, bl = tid >> 4;
  // staging map: consecutive lanes -> consecutive rows
  const int bl2 = tid & 15, cl2 = tid >> 4;
  const int cg = rank * NC + cl;
  const int bg = g * BG + bl;
  const int bg2 = g * BG + bl2;
  const float bz_r = bz[cg], br_r = br[cg], bh_r = bh[cg];

  float h_reg = 0.f;

  const int wv = tid >> 6, lane = tid & 63;
  const int mrow = lane & 15, q = lane >> 4;
  const int scO = bl * 18 + cl;

  // exchange fragment base: lane (wv,q,mrow) reads row mrow, cols wv*128+q*8 + {0,32,64,96}
  const uint64* hfb = (const uint64*)(hbG  + (size_t)mrow * HSZ + wv * 128 + q * 8);
  const uint64* rfb = (const uint64*)(rhbG + (size_t)mrow * HSZ + wv * 128 + q * 8);
  // poll base: source rank r0 = 8wv + (q>>1); ranks r0+2k at word (mrow>>2)
  const uint32* pfl = gf + (size_t)(8 * wv + (q >> 1)) * FLAG_U32_PER_RANK + (mrow >> 2);
  // producer flag word for this wave
  uint32* myflag = gf + (size_t)rank * FLAG_U32_PER_RANK + wv;

  // stage x[0], prefetch x[1]
  float4 px0, px1, px2, px3;
  {
    const float4* xs = (const float4*)(x + (size_t)bg2 * ISZ + cl2 * 16);
    px0 = xs[0]; px1 = xs[1]; px2 = xs[2]; px3 = xs[3];
    uint4* xd = (uint4*)(X_l + bl2 * LDA + cl2 * 16);
    xd[0] = make_uint4(f2x(px0.x, px0.y), f2x(px0.z, px0.w),
                       f2x(px1.x, px1.y), f2x(px1.z, px1.w));
    xd[1] = make_uint4(f2x(px2.x, px2.y), f2x(px2.z, px2.w),
                       f2x(px3.x, px3.y), f2x(px3.z, px3.w));
    const float4* xs1 = (const float4*)(x + ((size_t)1 * BSZ + bg2) * ISZ + cl2 * 16);
    px0 = xs1[0]; px1 = xs1[1]; px2 = xs1[2]; px3 = xs1[3];
  }
  __syncthreads();

  for (int t = 0; t < T_STEPS; ++t) {
    // ---- P1: x-part MFMAs for r,z,cand (K=64 slice per wave) ----
    f32x4 accR = {0.f, 0.f, 0.f, 0.f};
    f32x4 accZ = {0.f, 0.f, 0.f, 0.f};
    f32x4 accC = {0.f, 0.f, 0.f, 0.f};
    {
      const int kbx = wv * 64;
      const half8* Ap  = (const half8*)(X_l  + mrow * LDA + kbx + q * 8);
      const half8* BpR = (const half8*)(Wr_l + mrow * LDK + HSZ + kbx + q * 8);
      const half8* BpZ = (const half8*)(Wz_l + mrow * LDK + HSZ + kbx + q * 8);
      const half8* BpC = (const half8*)(Wh_l + mrow * LDK + HSZ + kbx + q * 8);
      half8 a0 = Ap[0], a1 = Ap[4];
      accR = MFMA(a0, BpR[0], accR);
      accZ = MFMA(a0, BpZ[0], accZ);
      accC = MFMA(a0, BpC[0], accC);
      accR = MFMA(a1, BpR[4], accR);
      accZ = MFMA(a1, BpZ[4], accZ);
      accC = MFMA(a1, BpC[4], accC);
    }

    // pre-load r weight fragments (off critical path)
    half8 br0, br1, br2, br3;
    {
      const half8* BpR = (const half8*)(Wr_l + mrow * LDK + wv * 128 + q * 8);
      br0 = BpR[0]; br1 = BpR[4]; br2 = BpR[8]; br3 = BpR[12];
    }

    // ---- P2: per-lane poll h flags (2t), direct fragment loads -> r h-MFMA ----
    {
      const uint32 need = (uint32)(2 * t);
      while (true) {
        uint32 v0 = ALD(pfl), v1 = ALD(pfl + 32), v2 = ALD(pfl + 64), v3 = ALD(pfl + 96);
        if (umin2(umin2(v0, v1), umin2(v2, v3)) >= need) break;
      }
    }
    HF fh0, fh1, fh2, fh3;
    {
      fh0.u[0] = ALD(hfb +  0); fh0.u[1] = ALD(hfb +  1);
      fh1.u[0] = ALD(hfb +  8); fh1.u[1] = ALD(hfb +  9);
      fh2.u[0] = ALD(hfb + 16); fh2.u[1] = ALD(hfb + 17);
      fh3.u[0] = ALD(hfb + 24); fh3.u[1] = ALD(hfb + 25);
      f32x4 aR1 = {0.f, 0.f, 0.f, 0.f};
      accR = MFMA(fh0.h8, br0, accR);
      aR1  = MFMA(fh1.h8, br1, aR1);
      accR = MFMA(fh2.h8, br2, accR);
      aR1  = MFMA(fh3.h8, br3, aR1);
      float* scw = scA + wv * 288;
      #pragma unroll
      for (int i = 0; i < 4; ++i) scw[(q * 4 + i) * 18 + mrow] = accR[i] + aR1[i];
    }
    __syncthreads();   // B2

    // ---- P3: r elementwise; publish rh; per-wave drain; wave flag (2t+1) ----
    {
      float rp = scA[scO] + scA[288 + scO] + scA[576 + scO] + scA[864 + scO] + br_r;
      float rhv = sigm(rp) * h_reg;
      __half hh = __float2half(rhv);
      uint32 lo = (uint32)__half_as_ushort(hh);
      uint32 hi = (uint32)__shfl_down((int)lo, 1);
      if (!(tid & 1))
        AST((uint32*)(rhbG + bl * HSZ + rank * NC + cl), lo | (hi << 16));
    }
    asm volatile("s_waitcnt vmcnt(0)" ::: "memory");
    if (lane == 0) AST(myflag, (uint32)(2 * t + 1));

    // ---- P4 (rh round-trip shadow): z h-part (reuse fh regs); x staging; x prefetch ----
    {
      const half8* BpZ = (const half8*)(Wz_l + mrow * LDK + wv * 128 + q * 8);
      accZ = MFMA(fh0.h8, BpZ[0], accZ);
      accZ = MFMA(fh1.h8, BpZ[4], accZ);
      accZ = MFMA(fh2.h8, BpZ[8], accZ);
      accZ = MFMA(fh3.h8, BpZ[12], accZ);
      float* scw = scB + wv * 288;
      #pragma unroll
      for (int i = 0; i < 4; ++i) scw[(q * 4 + i) * 18 + mrow] = accZ[i];
    }
    if (t + 1 < T_STEPS) {     // stage x_{t+1} (loaded last iteration)
      uint4* xd = (uint4*)(X_l + bl2 * LDA + cl2 * 16);
      xd[0] = make_uint4(f2x(px0.x, px0.y), f2x(px0.z, px0.w),
                         f2x(px1.x, px1.y), f2x(px1.z, px1.w));
      xd[1] = make_uint4(f2x(px2.x, px2.y), f2x(px2.z, px2.w),
                         f2x(px3.x, px3.y), f2x(px3.z, px3.w));
    }
    if (t + 2 < T_STEPS) {     // prefetch x_{t+2}
      const float4* xs = (const float4*)(x + ((size_t)(t + 2) * BSZ + bg2) * ISZ + cl2 * 16);
      px0 = xs[0]; px1 = xs[1]; px2 = xs[2]; px3 = xs[3];
    }

    // pre-load cand weight fragments
    half8 bc0, bc1, bc2, bc3;
    {
      const half8* BpC = (const half8*)(Wh_l + mrow * LDK + wv * 128 + q * 8);
      bc0 = BpC[0]; bc1 = BpC[4]; bc2 = BpC[8]; bc3 = BpC[12];
    }

    // ---- P6: per-lane poll rh flags (2t+1); direct loads -> cand MFMA ----
    {
      const uint32 need = (uint32)(2 * t + 1);
      while (true) {
        uint32 v0 = ALD(pfl), v1 = ALD(pfl + 32), v2 = ALD(pfl + 64), v3 = ALD(pfl + 96);
        if (umin2(umin2(v0, v1), umin2(v2, v3)) >= need) break;
      }
    }
    {
      HF fc0, fc1, fc2, fc3;
      fc0.u[0] = ALD(rfb +  0); fc0.u[1] = ALD(rfb +  1);
      fc1.u[0] = ALD(rfb +  8); fc1.u[1] = ALD(rfb +  9);
      fc2.u[0] = ALD(rfb + 16); fc2.u[1] = ALD(rfb + 17);
      fc3.u[0] = ALD(rfb + 24); fc3.u[1] = ALD(rfb + 25);
      f32x4 aC1 = {0.f, 0.f, 0.f, 0.f};
      accC = MFMA(fc0.h8, bc0, accC);
      aC1  = MFMA(fc1.h8, bc1, aC1);
      accC = MFMA(fc2.h8, bc2, accC);
      aC1  = MFMA(fc3.h8, bc3, aC1);
      float* scw = scC + wv * 288;
      #pragma unroll
      for (int i = 0; i < 4; ++i) scw[(q * 4 + i) * 18 + mrow] = accC[i] + aC1[i];
    }
    __syncthreads();   // B6

    // ---- P7: z finish, cand, h update; publish h; per-wave drain; flag (2t+2); out ----
    float hn;
    {
      float zp = scB[scO] + scB[288 + scO] + scB[576 + scO] + scB[864 + scO] + bz_r;
      float zg = sigm(zp);
      float cp = scC[scO] + scC[288 + scO] + scC[576 + scO] + scC[864 + scO] + bh_r;
      float cand = tanhx(cp);
      hn = (1.f - zg) * h_reg + zg * cand;
      h_reg = hn;
      __half hh = __float2half(hn);
      uint32 lo = (uint32)__half_as_ushort(hh);
      uint32 hi = (uint32)__shfl_down((int)lo, 1);
      if (!(tid & 1))
        AST((uint32*)(hbG + bl * HSZ + rank * NC + cl), lo | (hi << 16));
    }
    asm volatile("s_waitcnt vmcnt(0)" ::: "memory");
    if (lane == 0) AST(myflag, (uint32)(2 * t + 2));

    // out (HBM) store drains in the background of the next h round-trip
    out[((size_t)t * BSZ + bg) * HSZ + cg] = hn;
    if (t == T_STEPS - 1)
      out[((size_t)T_STEPS * BSZ + bg) * HSZ + cg] = hn;   // h_last
  }
}

extern "C" void kernel_launch(void* const* d_in, const int* in_sizes, int n_in,
                              void* d_out, int out_size, void* d_ws, size_t ws_size,
                              hipStream_t stream) {
  const float* x  = (const float*)d_in[0];
  const float* Wz = (const float*)d_in[1];
  const float* bz = (const float*)d_in[2];
  const float* Wr = (const float*)d_in[3];
  const float* br = (const float*)d_in[4];
  const float* Wh = (const float*)d_in[5];
  const float* bh = (const float*)d_in[6];
  float* out = (float*)d_out;

  // ws layout: [flags 8 groups * 32 ranks * 64B = 16KB][h_buf 128KB][rh_buf 128KB]
  uint32* flags = (uint32*)d_ws;
  unsigned short* h_buf  = (unsigned short*)((char*)d_ws + NG * GC * FLAG_U32_PER_RANK * 4);
  unsigned short* rh_buf = h_buf + NG * BG * HSZ;

  // zero flags + h0 (rh_buf is written before first read; no clear needed)
  hipMemsetAsync(d_ws, 0, NG * GC * FLAG_U32_PER_RANK * 4 + (size_t)NG * BG * HSZ * 2, stream);

  hipFuncSetAttribute(reinterpret_cast<const void*>(gru_persist),
                      hipFuncAttributeMaxDynamicSharedMemorySize, SMEM_BYTES);

  hipLaunchKernelGGL(gru_persist, dim3(NG * GC), dim3(256), SMEM_BYTES, stream,
                     x, Wz, bz, Wr, br, Wh, bh, out, h_buf, rh_buf, flags);
}